// Round 14
// baseline (204.375 us; speedup 1.0000x reference)
//
#include <hip/hip_runtime.h>

// n=2048 rows, f=32 features. Output row r = [emb[i] (32) | emb[j] (32) | sw[j]],
// i = r>>11, j = r&2047. Output = 2048*2048*65 floats = 1.09 GB, write-BW bound.
//
// v10: persistent v7. Same inner structure as v7 (best measured, 202-203 us:
// 8-slab intra-wave pipeline, double-buffered LDS, plain stores, 8 waves/CU
// via 61,440 B LDS pad -> 2 blocks/CU), but 512 blocks each loop over 16
// tiles (tile = b + 512k) instead of 8192 one-shot blocks. Tests the last
// live hypothesis: the ~35 us fixed component = 16 residency generations x
// serial block prologue (dependent load->scatter chain before first store).
//
// Arithmetic gift: tile mod 4 is invariant across k, so each wave's j-range
// j0 = (b&3)*512 + wave*128 is FIXED for all 16 tiles; only i advances by
// 128 per tile. Cross-tile the pipeline never breaks: phase-7's prefetch is
// the next tile's slab 0 (same j-slab), and the per-tile delta is one
// wave-uniform vi' (prefetched at phase 6) + 8 ds_writes per buffer.

#define NROWS 2048u
#define SLAB_ROWS 16u
#define SLAB_FLOATS (SLAB_ROWS * 65u)   // 1040 floats = 4160 B
#define SLAB_F4 (SLAB_FLOATS / 4u)      // 260 float4, exact
#define NBLOCKS 512u
#define NTILES 16u                      // tiles (512 rows each) per block
#define LDS_BYTES 61440u                // pad -> 2 blocks/CU (8 waves/CU)

typedef float f32x4 __attribute__((ext_vector_type(4)));

__global__ __launch_bounds__(256) void expand_persist(
    const float* __restrict__ emb,   // [2048*32]
    const float* __restrict__ sw,    // [2048]
    f32x4* __restrict__ out)         // flat output as float4
{
    extern __shared__ __align__(16) float dynlds[];   // 61,440 B requested

    const unsigned tid  = threadIdx.x;
    const unsigned wave = tid >> 6;
    const unsigned lane = tid & 63u;
    const unsigned b    = blockIdx.x;

    // Wave-fixed geometry. tile(k) = b + 512k; wave row0 = tile*512+wave*128.
    // j0 = row0 & 2047 = (b&3)*512 + wave*128  (k-invariant, 8 slabs walk
    // j0..j0+127). i(k) = row0>>11 = ((4b+wave)>>4) + 128k.
    const unsigned j0 = (b & 3u) * 512u + wave * 128u;
    const unsigned i0 = (b * 4u + wave) >> 4;
    const unsigned c     = lane & 31u;
    const unsigned rbase = (lane >> 5) * 8u;
    const unsigned d0 = (lane >> 3) * 65u + 32u + (lane & 7u) * 4u;

    float* buf0 = dynlds + (wave * 2u) * SLAB_FLOATS;
    float* buf1 = buf0 + SLAB_FLOATS;

    // ---- prologue (once per wave): a(tile0) into both buffers.
    float vi = emb[i0 * 32u + c];
#pragma unroll
    for (unsigned rp = 0; rp < 8u; ++rp) {
        buf0[(rbase + rp) * 65u + c] = vi;
        buf1[(rbase + rp) * 65u + c] = vi;
    }
    // slab 0 globals + scatter into buf0.
    {
        const f32x4* ej = (const f32x4*)(emb + (size_t)j0 * 32u);
        const f32x4 pa = ej[lane];
        const f32x4 pb = ej[lane + 64u];
        const float ps = sw[j0 + (lane & 15u)];
        buf0[d0 + 0u] = pa.x; buf0[d0 + 1u] = pa.y;
        buf0[d0 + 2u] = pa.z; buf0[d0 + 3u] = pa.w;
        buf0[d0 + 520u] = pb.x; buf0[d0 + 521u] = pb.y;
        buf0[d0 + 522u] = pb.z; buf0[d0 + 523u] = pb.w;
        if (lane < 16u) buf0[lane * 65u + 64u] = ps;
    }

    float viN = 0.0f;
#pragma unroll 1
    for (unsigned k = 0; k < NTILES; ++k) {
        const unsigned tb32 = (b + 512u * k) * 32u + wave * 8u;  // (row>>4) base
#pragma unroll
        for (unsigned s = 0; s < 8u; ++s) {
            float* CUR = (s & 1u) ? buf1 : buf0;
            float* NXT = (s & 1u) ? buf0 : buf1;
            const bool last = (k == NTILES - 1u) && (s == 7u);

            // prefetch next slab's globals (s=7 -> next tile's slab 0, same j0).
            f32x4 pa, pb;
            float ps = 0.0f;
            if (!last) {
                const unsigned jn = j0 + ((s + 1u) & 7u) * SLAB_ROWS;
                const f32x4* ej = (const f32x4*)(emb + (size_t)jn * 32u);
                pa = ej[lane];
                pb = ej[lane + 64u];
                ps = sw[jn + (lane & 15u)];
            }
            if (s == 6u && k + 1u < NTILES)
                viN = emb[(i0 + (k + 1u) * 128u) * 32u + c];   // next tile's a

            // drain CUR (tile k, slab s): 260 f4, unit stride, plain stores.
            const f32x4* L4 = (const f32x4*)CUR;
            const unsigned ob = (tb32 + s) * SLAB_F4;
#pragma unroll
            for (unsigned p = 0; p < 4u; ++p)
                out[ob + p * 64u + lane] = L4[p * 64u + lane];
            if (lane < 4u)
                out[ob + 256u + lane] = L4[256u + lane];

            // scatter prefetched slab into NXT; refresh a-part at tile edges.
            // (DS pipe is in-order per wave: these writes cannot pass the
            // ds_reads of NXT issued in the previous phase.)
            if (!last) {
                NXT[d0 + 0u] = pa.x; NXT[d0 + 1u] = pa.y;
                NXT[d0 + 2u] = pa.z; NXT[d0 + 3u] = pa.w;
                NXT[d0 + 520u] = pb.x; NXT[d0 + 521u] = pb.y;
                NXT[d0 + 522u] = pb.z; NXT[d0 + 523u] = pb.w;
                if (lane < 16u) NXT[lane * 65u + 64u] = ps;
                if (s == 7u) {          // buf0 enters tile k+1: a(viN)
#pragma unroll
                    for (unsigned rp = 0; rp < 8u; ++rp)
                        NXT[(rbase + rp) * 65u + c] = viN;
                } else if (s == 0u) {   // buf1 gets current tile's a(vi)
#pragma unroll
                    for (unsigned rp = 0; rp < 8u; ++rp)
                        NXT[(rbase + rp) * 65u + c] = vi;
                }
            }
        }
        vi = viN;
    }
}

extern "C" void kernel_launch(void* const* d_in, const int* in_sizes, int n_in,
                              void* d_out, int out_size, void* d_ws, size_t ws_size,
                              hipStream_t stream) {
    const float* emb = (const float*)d_in[0];   // [2048, 32] f32
    const float* sw  = (const float*)d_in[1];   // [2048] f32
    f32x4* out       = (f32x4*)d_out;

    expand_persist<<<dim3(NBLOCKS), dim3(256), LDS_BYTES, stream>>>(emb, sw, out);
}